// Round 10
// baseline (703.381 us; speedup 1.0000x reference)
//
#include <hip/hip_runtime.h>
#include <hip/hip_bf16.h>

#define N_NODES 100000
#define N_PAIRS 1600000
#define EDGE_NUM 30000
#define D 64
#define NEG_SLOPE 0.2f
#define NG 128  // pair-chunks for the XCD-pinned fill (grid = 8*NG)

// ---------------------------------------------------------------------------
// Prelude: fused histograms + X(f32)->Xbf(bf16) conversion.
// ---------------------------------------------------------------------------
__global__ __launch_bounds__(256) void prelude_kernel(
    const int* __restrict__ edges, const int* __restrict__ vertex,
    const float* __restrict__ X, __hip_bfloat16* __restrict__ Xbf,
    int* __restrict__ ecnt, int* __restrict__ vcnt)
{
    const int i = blockIdx.x * 256 + threadIdx.x;
    if (i < N_PAIRS) {
        atomicAdd(&ecnt[edges[i]], 1);
        atomicAdd(&vcnt[vertex[i]], 1);
    }
    const int c = i * 4;
    if (c < N_NODES * D) {
        float4 f = *(const float4*)&X[c];
        __hip_bfloat16 h[4] = {__float2bfloat16(f.x), __float2bfloat16(f.y),
                               __float2bfloat16(f.z), __float2bfloat16(f.w)};
        *(ushort4*)&Xbf[c] = *(const ushort4*)h;
    }
}

// ---------------------------------------------------------------------------
// scan: 16 elements/thread/chunk exclusive prefix
// ---------------------------------------------------------------------------
__device__ void scan_body(const int* cnt, int* off, int* cur, int n)
{
    __shared__ int wsum[16];
    __shared__ int s_carry;
    if (threadIdx.x == 0) s_carry = 0;
    __syncthreads();
    const int lane = threadIdx.x & 63;
    const int wave = threadIdx.x >> 6;

    for (int base = 0; base < n; base += 16384) {
        const int i0 = base + threadIdx.x * 16;
        int x[16];
        #pragma unroll
        for (int q = 0; q < 4; ++q) {
            const int ii = i0 + q * 4;
            if (ii + 3 < n) {
                int4 t = *(const int4*)&cnt[ii];
                x[q*4] = t.x; x[q*4+1] = t.y; x[q*4+2] = t.z; x[q*4+3] = t.w;
            } else {
                #pragma unroll
                for (int r = 0; r < 4; ++r) x[q*4+r] = (ii + r < n) ? cnt[ii + r] : 0;
            }
        }
        int tsum = 0;
        #pragma unroll
        for (int q = 0; q < 16; ++q) tsum += x[q];
        int sc = tsum;
        #pragma unroll
        for (int s = 1; s < 64; s <<= 1) {
            int y = __shfl_up(sc, s);
            if (lane >= s) sc += y;
        }
        if (lane == 63) wsum[wave] = sc;
        __syncthreads();
        int wbase = 0;
        for (int w = 0; w < wave; ++w) wbase += wsum[w];
        const int carry = s_carry;
        int run = carry + wbase + sc - tsum;
        int y[16];
        #pragma unroll
        for (int q = 0; q < 16; ++q) { y[q] = run; run += x[q]; }
        #pragma unroll
        for (int q = 0; q < 4; ++q) {
            const int ii = i0 + q * 4;
            if (ii + 3 < n) {
                *(int4*)&off[ii] = make_int4(y[q*4], y[q*4+1], y[q*4+2], y[q*4+3]);
                *(int4*)&cur[ii] = make_int4(y[q*4], y[q*4+1], y[q*4+2], y[q*4+3]);
            } else {
                #pragma unroll
                for (int r = 0; r < 4; ++r)
                    if (ii + r < n) { off[ii+r] = y[q*4+r]; cur[ii+r] = y[q*4+r]; }
            }
        }
        __syncthreads();
        if (threadIdx.x == 1023) s_carry = carry + wbase + sc;
        __syncthreads();
    }
    if (threadIdx.x == 0) off[n] = s_carry;
}

__global__ __launch_bounds__(1024) void scan2_kernel(
    int* ecnt, int* eoff, int* vcnt, int* voff)
{
    if (blockIdx.x == 0) scan_body(ecnt, eoff, ecnt, EDGE_NUM);
    else                 scan_body(vcnt, voff, vcnt, N_NODES);
}

// XCD-pinned fill (blockIdx%8 -> XCD): each XCD owns one key range.
__global__ __launch_bounds__(256) void fill_xcd_kernel(
    const int* __restrict__ edges, const int* __restrict__ vertex,
    int* __restrict__ ecur, int* __restrict__ vcur,
    int* __restrict__ evlist, int* __restrict__ velist)
{
    const int xcd = blockIdx.x & 7;
    const int grp = blockIdx.x >> 3;
    const int elo = xcd * (EDGE_NUM / 8);
    const int ehi = elo + (EDGE_NUM / 8);
    const int vlo = xcd * (N_NODES / 8);
    const int vhi = vlo + (N_NODES / 8);

    for (int i = grp * 256 + threadIdx.x; i < N_PAIRS; i += NG * 256) {
        const int e = edges[i];
        const int v = vertex[i];
        if (e >= elo && e < ehi) evlist[atomicAdd(&ecur[e], 1)] = v;
        if (v >= vlo && v < vhi) velist[atomicAdd(&vcur[v], 1)] = e;
    }
}

// ---------------------------------------------------------------------------
// Per-edge gather v2: one wave per 4 consecutive edges (type-uniform; W/bias
// loaded once per wave). Pair indices read with uniform-address loads (all
// lanes load the same velist/degV address -> 1 request + broadcast); 8
// independent (idx -> row) chains in flight; no bpermute, no register copies.
// ---------------------------------------------------------------------------
__global__ __launch_bounds__(256) void edge_gather_kernel(
    const __hip_bfloat16* __restrict__ Xbf, const float* __restrict__ degV,
    const float* __restrict__ Ww, const float* __restrict__ Wb,
    const int* __restrict__ eoff, const int* __restrict__ evlist,
    __hip_bfloat16* __restrict__ Xe)
{
    const int lane = threadIdx.x & 63;
    const int wave = threadIdx.x >> 6;
    const int ebase = blockIdx.x * 16 + wave * 4;         // 4-aligned run
    const int t = (ebase >= 10000) + (ebase >= 20000);    // uniform in wave

    float w[64];
    const float* wrow = Ww + ((size_t)(t + 1) * 64 + lane) * 64;
    #pragma unroll
    for (int i = 0; i < 64; i += 4) {
        float4 v4 = *(const float4*)(wrow + i);
        w[i] = v4.x; w[i+1] = v4.y; w[i+2] = v4.z; w[i+3] = v4.w;
    }
    const float b = Wb[(t + 1) * 64 + lane];
    const float* __restrict__ degt = degV + (size_t)t * N_NODES;
    const __hip_bfloat16* __restrict__ Xl = Xbf + lane;

    for (int q = 0; q < 4; ++q) {
        const int e = ebase + q;
        const int start = eoff[e], end = eoff[e + 1];

        float acc0 = 0.f, acc1 = 0.f, acc2 = 0.f, acc3 = 0.f, sdeg = 0.f;
        for (int j0 = start; j0 < end; j0 += 8) {
            int idx[8]; float f[8], s[8];
            #pragma unroll
            for (int u = 0; u < 8; ++u) {
                const int jj = (j0 + u < end) ? (j0 + u) : (end - 1);
                idx[u] = evlist[jj];                       // uniform load
            }
            #pragma unroll
            for (int u = 0; u < 8; ++u) f[u] = __bfloat162float(Xl[(size_t)idx[u] * D]);
            #pragma unroll
            for (int u = 0; u < 8; ++u)
                s[u] = (j0 + u < end) ? degt[idx[u]] : 0.f; // uniform load
            #pragma unroll
            for (int u = 0; u < 8; u += 4) {
                acc0 = fmaf(s[u],     f[u],     acc0);
                acc1 = fmaf(s[u + 1], f[u + 1], acc1);
                acc2 = fmaf(s[u + 2], f[u + 2], acc2);
                acc3 = fmaf(s[u + 3], f[u + 3], acc3);
                sdeg += (s[u] + s[u + 1]) + (s[u + 2] + s[u + 3]);
            }
        }
        const float acc = (acc0 + acc1) + (acc2 + acc3);

        // r[lane] = sum_i acc_i * W[lane][i] + sdeg*b  (sdeg is lane-uniform)
        float r0 = 0.f, r1 = 0.f, r2 = 0.f, r3 = 0.f;
        #pragma unroll
        for (int i = 0; i < 64; i += 4) {
            r0 = fmaf(__shfl(acc, i),     w[i],     r0);
            r1 = fmaf(__shfl(acc, i + 1), w[i + 1], r1);
            r2 = fmaf(__shfl(acc, i + 2), w[i + 2], r2);
            r3 = fmaf(__shfl(acc, i + 3), w[i + 3], r3);
        }
        const float r = ((r0 + r1) + (r2 + r3)) + sdeg * b;
        const int k = max(end - start, 1);
        Xe[(size_t)e * D + lane] = __float2bfloat16(r / (float)k);
    }
}

// ---------------------------------------------------------------------------
// Per-vertex v2: one wave per 4 vertices (W0 loaded once/wave). Uniform-load
// pair indices + bf16-Xe row gathers; x0 matvec via uniform X loads (no shfl);
// L2 norm + leaky relu.
// ---------------------------------------------------------------------------
__global__ __launch_bounds__(256) void vertex_gather_kernel(
    const float* __restrict__ X, const float* __restrict__ Ww,
    const float* __restrict__ Wb, const __hip_bfloat16* __restrict__ Xe,
    const int* __restrict__ voff, const int* __restrict__ velist,
    float* __restrict__ out)
{
    const int lane = threadIdx.x & 63;
    const int wave = threadIdx.x >> 6;
    const int vbase = blockIdx.x * 16 + wave * 4;

    float w[64];
    const float* wrow = Ww + (size_t)lane * 64;
    #pragma unroll
    for (int i = 0; i < 64; i += 4) {
        float4 t4 = *(const float4*)(wrow + i);
        w[i] = t4.x; w[i+1] = t4.y; w[i+2] = t4.z; w[i+3] = t4.w;
    }
    const float b = Wb[lane];
    const __hip_bfloat16* __restrict__ Xel = Xe + lane;

    for (int q = 0; q < 4; ++q) {
        const int v = vbase + q;
        const int start = voff[v], end = voff[v + 1];

        float acc0 = 0.f, acc1 = 0.f, acc2 = 0.f, acc3 = 0.f;
        for (int j0 = start; j0 < end; j0 += 8) {
            int idx[8]; float f[8], msk[8];
            #pragma unroll
            for (int u = 0; u < 8; ++u) {
                const int jj = (j0 + u < end) ? (j0 + u) : (end - 1);
                idx[u] = velist[jj];                       // uniform load
            }
            #pragma unroll
            for (int u = 0; u < 8; ++u) f[u] = __bfloat162float(Xel[(size_t)idx[u] * D]);
            #pragma unroll
            for (int u = 0; u < 8; ++u) msk[u] = (j0 + u < end) ? 1.f : 0.f;
            #pragma unroll
            for (int u = 0; u < 8; u += 4) {
                acc0 = fmaf(msk[u],     f[u],     acc0);
                acc1 = fmaf(msk[u + 1], f[u + 1], acc1);
                acc2 = fmaf(msk[u + 2], f[u + 2], acc2);
                acc3 = fmaf(msk[u + 3], f[u + 3], acc3);
            }
        }

        // x0[lane] = sum_i X[v][i]*W0[lane][i] + b  via uniform X loads
        float x0a = 0.f, x0b = 0.f, x0c = 0.f, x0d = 0.f;
        #pragma unroll
        for (int i = 0; i < 64; i += 4) {
            const float4 xq = *(const float4*)&X[(size_t)v * D + i];  // uniform
            x0a = fmaf(xq.x, w[i],     x0a);
            x0b = fmaf(xq.y, w[i + 1], x0b);
            x0c = fmaf(xq.z, w[i + 2], x0c);
            x0d = fmaf(xq.w, w[i + 3], x0d);
        }
        const float acc = ((acc0 + acc1) + (acc2 + acc3))
                        + (((x0a + x0b) + (x0c + x0d)) + b);

        float ss = acc * acc;
        #pragma unroll
        for (int off = 1; off < 64; off <<= 1) ss += __shfl_xor(ss, off);
        const float rn = sqrtf(ss);
        const float scale = (rn == 0.f) ? 0.f : 1.f / rn;
        const float y = acc * scale;
        out[(size_t)v * D + lane] = (y > 0.f) ? y : NEG_SLOPE * y;
    }
}

// ---------------------------------------------------------------------------
extern "C" void kernel_launch(void* const* d_in, const int* in_sizes, int n_in,
                              void* d_out, int out_size, void* d_ws, size_t ws_size,
                              hipStream_t stream)
{
    const float* X      = (const float*)d_in[0];
    const float* degV   = (const float*)d_in[1];
    const float* Ww     = (const float*)d_in[2];
    const float* Wb     = (const float*)d_in[3];
    const int*   vertex = (const int*)d_in[4];
    const int*   edges  = (const int*)d_in[5];
    float* out = (float*)d_out;

    // workspace layout (~30.5 MB)
    char* p = (char*)d_ws;
    __hip_bfloat16* Xe  = (__hip_bfloat16*)p;  p += (size_t)EDGE_NUM * D * 2;   // 3.84 MB
    __hip_bfloat16* Xbf = (__hip_bfloat16*)p;  p += (size_t)N_NODES * D * 2;    // 12.8 MB
    int* ib     = (int*)p;
    int* eoff   = ib;                  // 30004
    int* ecur   = ib + 30004;          // 30004
    int* voff   = ib + 60008;          // 100004
    int* vcur   = ib + 160012;         // 100004
    p += (size_t)260016 * 4;
    int* evlist = (int*)p;             p += (size_t)N_PAIRS * 4;
    int* velist = (int*)p;

    hipMemsetAsync(ib, 0, (size_t)260016 * 4, stream);

    prelude_kernel<<<(N_PAIRS + 255) / 256, 256, 0, stream>>>(
        edges, vertex, X, Xbf, ecur, vcur);

    scan2_kernel<<<2, 1024, 0, stream>>>(ecur, eoff, vcur, voff);

    fill_xcd_kernel<<<8 * NG, 256, 0, stream>>>(edges, vertex, ecur, vcur,
                                                evlist, velist);

    edge_gather_kernel<<<EDGE_NUM / 16, 256, 0, stream>>>(
        Xbf, degV, Ww, Wb, eoff, evlist, Xe);

    vertex_gather_kernel<<<N_NODES / 16, 256, 0, stream>>>(
        X, Ww, Wb, Xe, voff, velist, out);
}